// Round 6
// baseline (256.754 us; speedup 1.0000x reference)
//
#include <hip/hip_runtime.h>

#define NTOK 8192
#define NH 16
#define DD 64
#define NEGF -1e30f
#define LOG2E 1.4426950408889634f

typedef __attribute__((ext_vector_type(8))) short bf16x8;
typedef __attribute__((ext_vector_type(4))) float f32x4;

#define MFMA(a, b, c) __builtin_amdgcn_mfma_f32_16x16x32_bf16((a), (b), (c), 0, 0, 0)
#define EXP2(x) __builtin_amdgcn_exp2f(x)

static __device__ __forceinline__ unsigned short f2bf(float x) {
    union { float f; unsigned u; } c; c.f = x;
    unsigned r = (c.u + 0x7FFFu + ((c.u >> 16) & 1u)) >> 16;
    return (unsigned short)r;
}
static __device__ __forceinline__ float bf2f(unsigned short x) {
    union { unsigned u; float f; } c; c.u = ((unsigned)x) << 16;
    return c.f;
}

// ---------------- fused q/k fp32 -> bf16 convert (q gets softmax scale) ----------------
__global__ __launch_bounds__(256) void cvt_qk(const float* __restrict__ q, const float* __restrict__ k,
                                              unsigned short* __restrict__ Qb, unsigned short* __restrict__ Kb,
                                              float qscale, int n8) {
    int t = blockIdx.x * blockDim.x + threadIdx.x;
    const float* s; unsigned short* d; float sc;
    if (t < n8) { s = q; d = Qb; sc = qscale; }
    else       { s = k; d = Kb; sc = 1.0f; t -= n8; }
    const float4* s4 = (const float4*)s;
    float4 a = s4[2 * (size_t)t], b = s4[2 * (size_t)t + 1];
    union { unsigned short u[8]; uint4 q4; } o;
    o.u[0] = f2bf(a.x * sc); o.u[1] = f2bf(a.y * sc);
    o.u[2] = f2bf(a.z * sc); o.u[3] = f2bf(a.w * sc);
    o.u[4] = f2bf(b.x * sc); o.u[5] = f2bf(b.y * sc);
    o.u[6] = f2bf(b.z * sc); o.u[7] = f2bf(b.w * sc);
    *(uint4*)(d + 8 * (size_t)t) = o.q4;
}

// ---------------- v (h,n,d) fp32 -> blocked vt[h][n>>5][d][n&31] bf16 ----------------
__global__ __launch_bounds__(256) void transpose_v(const float* __restrict__ v,
                                                   unsigned short* __restrict__ vt) {
    int h = blockIdx.x >> 7;
    int n0 = (blockIdx.x & 127) << 6;
    __shared__ unsigned short t[64][65];
    int tid = threadIdx.x;
    int col = tid & 63;      // d
    int rr = tid >> 6;       // 0..3
    const float* src = v + ((size_t)(h * NTOK + n0)) * DD;
#pragma unroll
    for (int r = 0; r < 16; ++r) {
        int row = rr + r * 4;   // n local
        t[col][row] = f2bf(src[(size_t)row * DD + col]);
    }
    __syncthreads();
    int d = tid >> 2, ch = tid & 3;
    union { unsigned short u[16]; uint4 q[2]; } tmp;
#pragma unroll
    for (int j = 0; j < 16; ++j) tmp.u[j] = t[d][ch * 16 + j];
    int b = (n0 >> 5) + (ch >> 1);
    unsigned short* dst = vt + ((size_t)(h * 256 + b)) * 2048 + d * 32 + (ch & 1) * 16;
    ((uint4*)dst)[0] = tmp.q[0];
    ((uint4*)dst)[1] = tmp.q[1];
}

// ---------------- level-1 pool: K1/V1 row-major + Vt1 blocked ----------------
__global__ __launch_bounds__(256) void pool1_kernel(const float* __restrict__ k, const float* __restrict__ v,
                                                    unsigned short* __restrict__ k1,
                                                    unsigned short* __restrict__ v1r,
                                                    unsigned short* __restrict__ vt1) {
    int tid = blockIdx.x * blockDim.x + threadIdx.x;   // NH*1024*64
    int d = tid & 63;
    int c = (tid >> 6) & 1023;
    int h = tid >> 16;
    size_t base = ((size_t)(h * NTOK + c * 8)) * DD + d;
    float ks = 0.f, vs = 0.f;
#pragma unroll
    for (int r = 0; r < 8; ++r) {
        ks += k[base + (size_t)r * DD];
        vs += v[base + (size_t)r * DD];
    }
    ks *= 0.125f; vs *= 0.125f;
    k1[((size_t)(h * 1024 + c)) * DD + d] = f2bf(ks);
    v1r[((size_t)(h * 1024 + c)) * DD + d] = f2bf(vs);
    vt1[((size_t)(h * 32 + (c >> 5))) * 2048 + d * 32 + (c & 31)] = f2bf(vs);
}

// ---------------- level-2 pool ----------------
__global__ __launch_bounds__(256) void pool2_kernel(const unsigned short* __restrict__ k1,
                                                    const unsigned short* __restrict__ v1r,
                                                    unsigned short* __restrict__ k2,
                                                    unsigned short* __restrict__ v2r,
                                                    unsigned short* __restrict__ vt2) {
    int tid = blockIdx.x * blockDim.x + threadIdx.x;   // NH*128*64
    int d = tid & 63;
    int c = (tid >> 6) & 127;
    int h = tid >> 13;
    float ks = 0.f, vs = 0.f;
#pragma unroll
    for (int j = 0; j < 8; ++j) {
        ks += bf2f(k1[((size_t)(h * 1024 + c * 8 + j)) * DD + d]);
        vs += bf2f(v1r[((size_t)(h * 1024 + c * 8 + j)) * DD + d]);
    }
    ks *= 0.125f; vs *= 0.125f;
    k2[((size_t)(h * 128 + c)) * DD + d] = f2bf(ks);
    v2r[((size_t)(h * 128 + c)) * DD + d] = f2bf(vs);
    vt2[((size_t)(h * 4 + (c >> 5))) * 2048 + d * 32 + (c & 31)] = f2bf(vs);
}

// ---------------- level-3 pool (16 real chunks, padded to 32) ----------------
__global__ __launch_bounds__(256) void pool3_kernel(const unsigned short* __restrict__ k2,
                                                    const unsigned short* __restrict__ v2r,
                                                    unsigned short* __restrict__ k3,
                                                    unsigned short* __restrict__ vt3) {
    int tid = blockIdx.x * blockDim.x + threadIdx.x;   // NH*32*64
    int d = tid & 63;
    int c = (tid >> 6) & 31;
    int h = tid >> 11;
    float ks = 0.f, vs = 0.f;
    if (c < 16) {
#pragma unroll
        for (int j = 0; j < 8; ++j) {
            ks += bf2f(k2[((size_t)(h * 128 + c * 8 + j)) * DD + d]);
            vs += bf2f(v2r[((size_t)(h * 128 + c * 8 + j)) * DD + d]);
        }
        ks *= 0.125f; vs *= 0.125f;
    }
    k3[((size_t)(h * 32 + c)) * DD + d] = f2bf(ks);
    vt3[(size_t)h * 2048 + d * 32 + c] = f2bf(vs);
}

struct KG { bf16x8 k0, k1, k2, k3; };
struct VG { bf16x8 v0, v1, v2, v3; };

// ---------------- per-level inner loop: 32 queries (2 tiles), 32 keys/iter ----------------
// Depth-2 ping-pong pipeline: prologue puts groups i and i+1 in flight (16 loads);
// each STEP computes group i and issues group i+2 into the SAME ping buffer.
// All waits are counted vmcnt(12); issue->use gap = 2 group-computes.
template<int S, bool L0>
__device__ __forceinline__ void do_level(
    const unsigned short* __restrict__ Kh, const unsigned short* __restrict__ Vth,
    int c0_top, int c0_lo, int Qs, float gp, int g, int c,
    bf16x8 qa0, bf16x8 qa1, bf16x8 qb0, bf16x8 qb1,
    float& m, float& lA, float& lB, f32x4* oA, f32x4* oB) {

    const float gps = gp * (float)S;
    const int i_qA = Qs + c, i_qB = Qs + 16 + c;
    const float negfbA = gps * (float)(8 * g) + gp * (float)(S - 1) - gp * (float)i_qA;
    const float negfbB = negfbA - 16.f * gp;
    int c_allA = -0x40000000, c_allB = -0x40000000;
    if (!L0) {
        int numA = Qs - 128 - (S - 1);
        int numB = numA + 16;
        if (numA >= 0) c_allA = numA / S;
        if (numB >= 0) c_allB = numB / S;
    }
    const unsigned short* kb = Kh + ((size_t)(8 * (c >> 2) + (c & 3))) * DD + g * 8;
    const unsigned short* vb = Vth + c * 32 + g * 8;

    auto LOADK = [&](int c0) -> KG {
        KG r;
        const unsigned short* ka = kb + (size_t)c0 * DD;
        r.k0 = *(const bf16x8*)(const void*)(ka);
        r.k1 = *(const bf16x8*)(const void*)(ka + 32);
        r.k2 = *(const bf16x8*)(const void*)(ka + 4 * DD);
        r.k3 = *(const bf16x8*)(const void*)(ka + 4 * DD + 32);
        return r;
    };
    auto LOADV = [&](int c0) -> VG {
        VG r;
        const unsigned short* va = vb + (size_t)(c0 >> 5) * 2048;
        r.v0 = *(const bf16x8*)(const void*)(va);
        r.v1 = *(const bf16x8*)(const void*)(va + 512);
        r.v2 = *(const bf16x8*)(const void*)(va + 1024);
        r.v3 = *(const bf16x8*)(const void*)(va + 1536);
        return r;
    };

    // STEP: compute group c0 from (kg,vg); refill (kg,vg) with group c0-64 (clamped)
    auto STEP = [&](KG& kg, VG& vg, int c0) {
        __builtin_amdgcn_s_setprio(1);
        f32x4 z = {0.f, 0.f, 0.f, 0.f};
        f32x4 sAA = MFMA(kg.k1, qa1, MFMA(kg.k0, qa0, z));
        f32x4 sAB = MFMA(kg.k3, qa1, MFMA(kg.k2, qa0, z));
        f32x4 sBA = MFMA(kg.k1, qb1, MFMA(kg.k0, qb0, z));
        f32x4 sBB = MFMA(kg.k3, qb1, MFMA(kg.k2, qb0, z));
        __builtin_amdgcn_s_setprio(0);

        int cp = c0 - 64; if (cp < c0_lo) cp = c0_lo;
        kg = LOADK(cp);                      // issue K for group i+2

        float c0f = (float)c0;
        float svA[8], svB[8];
        bool fastA = L0 ? ((c0 >= Qs - 112) && (c0 + 31 <= Qs)) : (c0 + 31 <= c_allA);
        bool fastB = L0 ? ((c0 >= Qs - 96) && (c0 + 31 <= Qs + 16)) : (c0 + 31 <= c_allB);
        if (fastA) {
            float u0 = fmaf(gps, c0f, negfbA);
            svA[0] = sAA[0] + u0;
            svA[1] = sAA[1] + fmaf(gps, 1.f, u0);
            svA[2] = sAA[2] + fmaf(gps, 2.f, u0);
            svA[3] = sAA[3] + fmaf(gps, 3.f, u0);
            svA[4] = sAB[0] + fmaf(gps, 4.f, u0);
            svA[5] = sAB[1] + fmaf(gps, 5.f, u0);
            svA[6] = sAB[2] + fmaf(gps, 6.f, u0);
            svA[7] = sAB[3] + fmaf(gps, 7.f, u0);
        } else {
#pragma unroll
            for (int r = 0; r < 4; ++r) {
                int cA = c0 + 8 * g + r, cB = cA + 4;
                int jA = L0 ? cA : (cA * S + S - 1);
                int jB = L0 ? cB : (cB * S + S - 1);
                int dA = i_qA - jA, dB = i_qA - jB;
                bool aA = L0 ? ((unsigned)dA <= 127u) : (dA >= 128);
                bool aB = L0 ? ((unsigned)dB <= 127u) : (dB >= 128);
                svA[r]     = aA ? fmaf(-gp, (float)dA, sAA[r]) : NEGF;
                svA[r + 4] = aB ? fmaf(-gp, (float)dB, sAB[r]) : NEGF;
            }
        }
        if (fastB) {
            float u0 = fmaf(gps, c0f, negfbB);
            svB[0] = sBA[0] + u0;
            svB[1] = sBA[1] + fmaf(gps, 1.f, u0);
            svB[2] = sBA[2] + fmaf(gps, 2.f, u0);
            svB[3] = sBA[3] + fmaf(gps, 3.f, u0);
            svB[4] = sBB[0] + fmaf(gps, 4.f, u0);
            svB[5] = sBB[1] + fmaf(gps, 5.f, u0);
            svB[6] = sBB[2] + fmaf(gps, 6.f, u0);
            svB[7] = sBB[3] + fmaf(gps, 7.f, u0);
        } else {
#pragma unroll
            for (int r = 0; r < 4; ++r) {
                int cA = c0 + 8 * g + r, cB = cA + 4;
                int jA = L0 ? cA : (cA * S + S - 1);
                int jB = L0 ? cB : (cB * S + S - 1);
                int dA = i_qB - jA, dB = i_qB - jB;
                bool aA = L0 ? ((unsigned)dA <= 127u) : (dA >= 128);
                bool aB = L0 ? ((unsigned)dB <= 127u) : (dB >= 128);
                svB[r]     = aA ? fmaf(-gp, (float)dA, sBA[r]) : NEGF;
                svB[r + 4] = aB ? fmaf(-gp, (float)dB, sBB[r]) : NEGF;
            }
        }

        // wave-uniform deferred max (no cross-lane reduce in steady state)
        float tm = fmaxf(
            fmaxf(fmaxf(fmaxf(svA[0], svA[1]), fmaxf(svA[2], svA[3])),
                  fmaxf(fmaxf(svA[4], svA[5]), fmaxf(svA[6], svA[7]))),
            fmaxf(fmaxf(fmaxf(svB[0], svB[1]), fmaxf(svB[2], svB[3])),
                  fmaxf(fmaxf(svB[4], svB[5]), fmaxf(svB[6], svB[7]))));
        if (__any(tm > m + 8.f)) {          // rare: newest-first => scores decay
            float wm = tm;
            wm = fmaxf(wm, __shfl_xor(wm, 1));
            wm = fmaxf(wm, __shfl_xor(wm, 2));
            wm = fmaxf(wm, __shfl_xor(wm, 4));
            wm = fmaxf(wm, __shfl_xor(wm, 8));
            wm = fmaxf(wm, __shfl_xor(wm, 16));
            wm = fmaxf(wm, __shfl_xor(wm, 32));
            float mn = fmaxf(m, wm);
            float sf = EXP2(m - mn);        // m=-1e30 -> 0
            m = mn;
            lA *= sf; lB *= sf;
            oA[0] *= sf; oA[1] *= sf; oA[2] *= sf; oA[3] *= sf;
            oB[0] *= sf; oB[1] *= sf; oB[2] *= sf; oB[3] *= sf;
        }

        union { unsigned u32[4]; bf16x8 v8; } pfA, pfB;
        {
            float p[8];
#pragma unroll
            for (int r = 0; r < 8; ++r) p[r] = EXP2(svA[r] - m);
            lA += ((p[0] + p[1]) + (p[2] + p[3])) + ((p[4] + p[5]) + (p[6] + p[7]));
#pragma unroll
            for (int j = 0; j < 4; ++j)
                asm("v_cvt_pk_bf16_f32 %0, %1, %2" : "=v"(pfA.u32[j]) : "v"(p[2 * j]), "v"(p[2 * j + 1]));
        }
        {
            float p[8];
#pragma unroll
            for (int r = 0; r < 8; ++r) p[r] = EXP2(svB[r] - m);
            lB += ((p[0] + p[1]) + (p[2] + p[3])) + ((p[4] + p[5]) + (p[6] + p[7]));
#pragma unroll
            for (int j = 0; j < 4; ++j)
                asm("v_cvt_pk_bf16_f32 %0, %1, %2" : "=v"(pfB.u32[j]) : "v"(p[2 * j]), "v"(p[2 * j + 1]));
        }

        __builtin_amdgcn_s_setprio(1);
        oA[0] = MFMA(vg.v0, pfA.v8, oA[0]);
        oB[0] = MFMA(vg.v0, pfB.v8, oB[0]);
        oA[1] = MFMA(vg.v1, pfA.v8, oA[1]);
        oB[1] = MFMA(vg.v1, pfB.v8, oB[1]);
        oA[2] = MFMA(vg.v2, pfA.v8, oA[2]);
        oB[2] = MFMA(vg.v2, pfB.v8, oB[2]);
        oA[3] = MFMA(vg.v3, pfA.v8, oA[3]);
        oB[3] = MFMA(vg.v3, pfB.v8, oB[3]);
        __builtin_amdgcn_s_setprio(0);

        vg = LOADV(cp);                      // issue V for group i+2
    };

    int c1 = c0_top - 32; if (c1 < c0_lo) c1 = c0_lo;
    KG kA = LOADK(c0_top); VG vA = LOADV(c0_top);
    KG kB = LOADK(c1);     VG vB = LOADV(c1);

    int c0 = c0_top;
    while (c0 - 32 >= c0_lo) {
        STEP(kA, vA, c0);
        STEP(kB, vB, c0 - 32);
        c0 -= 64;
    }
    if (c0 >= c0_lo) STEP(kA, vA, c0);
}

// ---------------- main attention: 2 waves/block, 32 queries/wave ----------------
__global__ __launch_bounds__(128, 3) void attn_mfma(
    const unsigned short* __restrict__ Qb, const unsigned short* __restrict__ Kb,
    const unsigned short* __restrict__ Vtb,
    const unsigned short* __restrict__ K1, const unsigned short* __restrict__ Vt1,
    const unsigned short* __restrict__ K2, const unsigned short* __restrict__ Vt2,
    const unsigned short* __restrict__ K3, const unsigned short* __restrict__ Vt3,
    const float* __restrict__ gam, float* __restrict__ out) {
    const int lane = threadIdx.x & 63;
    const int wid = threadIdx.x >> 6;
    const int h = blockIdx.x & 15;        // 2 heads per XCD (L2 locality)
    const int qt = 127 - (blockIdx.x >> 4); // LPT: heaviest q-tiles dispatched first
    const int Qs = (qt << 6) + wid * 32;
    const int g = lane >> 4;
    const int c = lane & 15;

    const float g0 = gam[0] * LOG2E, g1 = gam[1] * LOG2E;
    const float g2 = gam[2] * LOG2E, g3 = gam[3] * LOG2E;

    const unsigned short* QrowA = Qb + ((size_t)(h * NTOK + Qs + c)) * DD;
    bf16x8 qa0 = *(const bf16x8*)(const void*)(QrowA + g * 8);
    bf16x8 qa1 = *(const bf16x8*)(const void*)(QrowA + 32 + g * 8);
    const unsigned short* QrowB = QrowA + 16 * DD;
    bf16x8 qb0 = *(const bf16x8*)(const void*)(QrowB + g * 8);
    bf16x8 qb1 = *(const bf16x8*)(const void*)(QrowB + 32 + g * 8);

    f32x4 oA[4], oB[4];
#pragma unroll
    for (int t = 0; t < 4; ++t) { oA[t] = (f32x4){0.f,0.f,0.f,0.f}; oB[t] = (f32x4){0.f,0.f,0.f,0.f}; }
    float m = NEGF, lA = 0.f, lB = 0.f;

    // level 0 (newest first)
    {
        int lo = Qs - 127; if (lo < 0) lo = 0; lo &= ~31;
        do_level<1, true>(Kb + (size_t)h * NTOK * DD, Vtb + (size_t)h * 256 * 2048,
                          Qs, lo, Qs, g0, g, c, qa0, qa1, qb0, qb1, m, lA, lB, oA, oB);
    }
    {
        int cm = Qs - 104;                 // (Qs+31)-128-7
        if (cm >= 0)
            do_level<8, false>(K1 + (size_t)h * 1024 * DD, Vt1 + (size_t)h * 32 * 2048,
                               (cm / 8) & ~31, 0, Qs, g1, g, c, qa0, qa1, qb0, qb1, m, lA, lB, oA, oB);
    }
    {
        int cm = Qs - 160;                 // (Qs+31)-128-63
        if (cm >= 0)
            do_level<64, false>(K2 + (size_t)h * 128 * DD, Vt2 + (size_t)h * 4 * 2048,
                                (cm / 64) & ~31, 0, Qs, g2, g, c, qa0, qa1, qb0, qb1, m, lA, lB, oA, oB);
    }
    {
        int cm = Qs - 608;                 // (Qs+31)-128-511
        if (cm >= 0)
            do_level<512, false>(K3 + (size_t)h * 32 * DD, Vt3 + (size_t)h * 2048,
                                 0, 0, Qs, g3, g, c, qa0, qa1, qb0, qb1, m, lA, lB, oA, oB);
    }

    // final l reduce over the 4 g-lanes of each query column
    float ltA = lA + __shfl_xor(lA, 16); ltA += __shfl_xor(ltA, 32);
    float ltB = lB + __shfl_xor(lB, 16); ltB += __shfl_xor(ltB, 32);
    float invA = 1.0f / fmaxf(ltA, 1e-8f);
    float invB = 1.0f / fmaxf(ltB, 1e-8f);

    float* orowA = out + ((size_t)(h * NTOK + Qs + c)) * DD;
    float* orowB = orowA + 16 * DD;
#pragma unroll
    for (int db = 0; db < 4; ++db) {
        float4 x;
        x.x = oA[db][0] * invA; x.y = oA[db][1] * invA;
        x.z = oA[db][2] * invA; x.w = oA[db][3] * invA;
        *(float4*)(orowA + db * 16 + 4 * g) = x;
        float4 y;
        y.x = oB[db][0] * invB; y.y = oB[db][1] * invB;
        y.z = oB[db][2] * invB; y.w = oB[db][3] * invB;
        *(float4*)(orowB + db * 16 + 4 * g) = y;
    }
}

extern "C" void kernel_launch(void* const* d_in, const int* in_sizes, int n_in,
                              void* d_out, int out_size, void* d_ws, size_t ws_size,
                              hipStream_t stream) {
    const float* q = (const float*)d_in[0];
    const float* k = (const float*)d_in[1];
    const float* v = (const float*)d_in[2];
    const float* gam = (const float*)d_in[3];
    float* out = (float*)d_out;

    char* w = (char*)d_ws;
    const size_t bigN = (size_t)NH * NTOK * DD * sizeof(unsigned short);
    unsigned short* Qb  = (unsigned short*)w;  w += bigN;
    unsigned short* Kb  = (unsigned short*)w;  w += bigN;
    unsigned short* Vtb = (unsigned short*)w;  w += bigN;                       // blocked
    unsigned short* K1  = (unsigned short*)w;  w += (size_t)NH * 1024 * DD * 2;
    unsigned short* V1r = (unsigned short*)w;  w += (size_t)NH * 1024 * DD * 2;
    unsigned short* Vt1 = (unsigned short*)w;  w += (size_t)NH * 1024 * DD * 2; // blocked
    unsigned short* K2  = (unsigned short*)w;  w += (size_t)NH * 128 * DD * 2;
    unsigned short* V2r = (unsigned short*)w;  w += (size_t)NH * 128 * DD * 2;
    unsigned short* Vt2 = (unsigned short*)w;  w += (size_t)NH * 128 * DD * 2;  // blocked
    unsigned short* K3  = (unsigned short*)w;  w += (size_t)NH * 32 * DD * 2;
    unsigned short* Vt3 = (unsigned short*)w;  w += (size_t)NH * 32 * DD * 2;   // blocked

    int n8 = NH * NTOK * DD / 8;
    const float qscale = 0.125f * LOG2E;   // fold softmax scale + log2e into Q
    cvt_qk<<<2 * n8 / 256, 256, 0, stream>>>(q, k, Qb, Kb, qscale, n8);
    transpose_v<<<NH * (NTOK / 64), 256, 0, stream>>>(v, Vtb);
    pool1_kernel<<<NH * 1024 * DD / 256, 256, 0, stream>>>(k, v, K1, V1r, Vt1);
    pool2_kernel<<<NH * 128 * DD / 256, 256, 0, stream>>>(K1, V1r, K2, V2r, Vt2);
    pool3_kernel<<<NH * 32 * DD / 256, 256, 0, stream>>>(K2, V2r, K3, Vt3);

    attn_mfma<<<NH * 128, 128, 0, stream>>>(Qb, Kb, Vtb, K1, Vt1, K2, Vt2, K3, Vt3, gam, out);
}